// Round 13
// baseline (183.221 us; speedup 1.0000x reference)
//
#include <hip/hip_runtime.h>
#include <hip/hip_bf16.h>

#define H_    32
#define HKV_  8
#define D_    128
#define HID_  4096
#define NQKV  6144            // 4096 + 1024 + 1024
#define SPLIT 128             // split-K for the GEMVs (rows per chunk = 32)
#define CHUNK 256             // tokens per attention block
#define NIT   (CHUNK / 8)     // 32 iterations, 8 tokens each per wave
#define S_    32768
#define NCHUNK (S_ / CHUNK)   // 128
#define SCALE_ 0.08838834764831843f  // 1/sqrt(128)
#define BASE_  8.0f           // fixed softmax base: wgt = exp(s - 8), exact (cancels)

// workspace layout (float offsets)
#define WS_QKV_PART 0                       // [SPLIT][NQKV]          786432
#define WS_QKV      786432                  // [NQKV]                 6144
#define WS_PV_C     792576                  // [NCHUNK][HKV][4][D]    524288
#define WS_L_C      1316864                 // [NCHUNK][HKV][4]       4096
#define WS_ATTN     1320960                 // [H*D]                  4096
#define WS_OPART    1325056                 // [SPLIT][HID]           524288 (sweep scratch too)

// ---------------- kernel 0: DIAGNOSTIC sweep of kqx+vqx, GEMV-shaped ----------------
// 1024 blocks x 256 thr; block b reads 128 KB of each array, contiguous,
// 4 KB per instruction-group, unroll 8 (same shape as the 6 TB/s GEMV).
// XOR-accumulate, 1 int per thread written -> no DCE, negligible write traffic.
__global__ __launch_bounds__(256) void k_sweep(
    const int* __restrict__ kqx, const int* __restrict__ vqx,
    int* __restrict__ sink)
{
    const int tid = threadIdx.x;
    const int4* kp = (const int4*)kqx + (size_t)blockIdx.x * 8192 + tid;
    const int4* vp = (const int4*)vqx + (size_t)blockIdx.x * 8192 + tid;
    int4 acc = {0, 0, 0, 0};
    #pragma unroll 8
    for (int i = 0; i < 32; ++i) {
        const int4 a = kp[i * 256];
        acc.x ^= a.x; acc.y ^= a.y; acc.z ^= a.z; acc.w ^= a.w;
    }
    #pragma unroll 8
    for (int i = 0; i < 32; ++i) {
        const int4 a = vp[i * 256];
        acc.x ^= a.x; acc.y ^= a.y; acc.z ^= a.z; acc.w ^= a.w;
    }
    sink[blockIdx.x * 256 + tid] = acc.x ^ acc.y ^ acc.z ^ acc.w;
}

// ---------------- kernel 1: QKV GEMV split-K partials ----------------
__global__ __launch_bounds__(256) void k_qkv_part(
    const float* __restrict__ hid, const float* __restrict__ Wq,
    const float* __restrict__ Wk, const float* __restrict__ Wv,
    float* __restrict__ part)
{
    const int j0 = blockIdx.x * 1024 + threadIdx.x * 4;   // 6 col-blocks of 1024
    const int i0 = blockIdx.y * (HID_ / SPLIT);           // 32-row chunk
    __shared__ float hs[HID_ / SPLIT];
    if (threadIdx.x < HID_ / SPLIT) hs[threadIdx.x] = hid[i0 + threadIdx.x];
    __syncthreads();

    const float* W; int ldw; int col;
    if (j0 < 4096)       { W = Wq; ldw = 4096; col = j0; }
    else if (j0 < 5120)  { W = Wk; ldw = 1024; col = j0 - 4096; }
    else                 { W = Wv; ldw = 1024; col = j0 - 5120; }

    float4 acc = {0.f, 0.f, 0.f, 0.f};
    const float* p = W + (size_t)i0 * ldw + col;
    #pragma unroll 8
    for (int i = 0; i < HID_ / SPLIT; ++i) {
        const float4 wv = *(const float4*)(p + (size_t)i * ldw);
        const float h = hs[i];
        acc.x += h * wv.x; acc.y += h * wv.y; acc.z += h * wv.z; acc.w += h * wv.w;
    }
    *(float4*)&part[(size_t)blockIdx.y * NQKV + j0] = acc;
}

// ---------------- kernel 2: reduce partials + RoPE ----------------
__global__ __launch_bounds__(256) void k_qkv_reduce(
    const float* __restrict__ part, const float* __restrict__ cosv,
    const float* __restrict__ sinv, float* __restrict__ qkv)
{
    const int j = blockIdx.x * 256 + threadIdx.x;  // 24 blocks
    float s = 0.f;
    #pragma unroll 8
    for (int k = 0; k < SPLIT; ++k) s += part[(size_t)k * NQKV + j];
    __shared__ float buf[256];
    buf[threadIdx.x] = s;
    __syncthreads();
    float out = s;
    if (j < 5120) {  // q and k get RoPE; v passes through
        const int d = j & 127;
        const float rot = (d < 64) ? -buf[threadIdx.x + 64] : buf[threadIdx.x - 64];
        out = s * cosv[d] + rot * sinv[d];
    }
    qkv[j] = out;
}

// ---------------- kernel 3: fused attention, depth-4 register pipeline ----------------
// block = 256 thr = 4 waves; wave g = head (kh*4+g); lane = t*8+j.
// 4 static staging slots (slot = it&3, compile-time under unroll 4) hold
// K/V/scales for iterations it..it+3 -> 16-24 KB per wave in flight through
// the dot/shfl/exp tail. __launch_bounds__(256,2) lets the allocator keep
// ~185 VGPRs instead of sinking the loads (R7's failure mode).
// Fixed-base softmax: wgt = exp(s - 8), exact (base cancels in final ratio).
__global__ __launch_bounds__(256, 2) void k_attn(
    const int* __restrict__ kqx, const float* __restrict__ kscale,
    const int* __restrict__ vqx, const float* __restrict__ vscale,
    const float* __restrict__ qkv, float* __restrict__ pv_c,
    float* __restrict__ l_c)
{
    const int kh = blockIdx.x;
    const int c  = blockIdx.y;
    const int c0 = c * CHUNK;
    const int tid = threadIdx.x;
    const int g = tid >> 6;          // wave = head-in-group
    const int l = tid & 63;
    const int t = l >> 3, j = l & 7;

    float4 qf[4];
    #pragma unroll
    for (int k = 0; k < 4; ++k)
        qf[k] = *(const float4*)&qkv[(kh * 4 + g) * D_ + (j + 8 * k) * 4];

    float ls = 0.f;
    float4 acc[4];
    #pragma unroll
    for (int k = 0; k < 4; ++k) acc[k] = make_float4(0.f, 0.f, 0.f, 0.f);

    int4 ks[4][4], vs4[4][4];
    float ksc[4], vsc[4];

#define LOADIT(slot, it_) do {                                               \
        const int tok_ = c0 + (it_) * 8 + t;                                 \
        const size_t row_ = ((size_t)tok_ * HKV_ + kh) * D_;                 \
        _Pragma("unroll")                                                    \
        for (int k2 = 0; k2 < 4; ++k2) {                                     \
            ks[slot][k2]  = *(const int4*)(kqx + row_ + (j + 8 * k2) * 4);   \
            vs4[slot][k2] = *(const int4*)(vqx + row_ + (j + 8 * k2) * 4);   \
        }                                                                    \
        ksc[slot] = kscale[(size_t)tok_ * HKV_ + kh];                        \
        vsc[slot] = vscale[(size_t)tok_ * HKV_ + kh];                        \
    } while (0)

    LOADIT(0, 0); LOADIT(1, 1); LOADIT(2, 2);

    #pragma unroll 4
    for (int it = 0; it < NIT; ++it) {
        const int s = it & 3;            // static per unrolled copy
        if (it + 3 < NIT) LOADIT((it + 3) & 3, it + 3);

        float d0 = (float)ks[s][0].x * qf[0].x + (float)ks[s][0].y * qf[0].y +
                   (float)ks[s][0].z * qf[0].z + (float)ks[s][0].w * qf[0].w;
        float d1 = (float)ks[s][1].x * qf[1].x + (float)ks[s][1].y * qf[1].y +
                   (float)ks[s][1].z * qf[1].z + (float)ks[s][1].w * qf[1].w;
        float d2 = (float)ks[s][2].x * qf[2].x + (float)ks[s][2].y * qf[2].y +
                   (float)ks[s][2].z * qf[2].z + (float)ks[s][2].w * qf[2].w;
        float d3 = (float)ks[s][3].x * qf[3].x + (float)ks[s][3].y * qf[3].y +
                   (float)ks[s][3].z * qf[3].z + (float)ks[s][3].w * qf[3].w;
        float dot = (d0 + d1) + (d2 + d3);
        dot += __shfl_xor(dot, 1, 64);
        dot += __shfl_xor(dot, 2, 64);
        dot += __shfl_xor(dot, 4, 64);

        const float wgt = __expf(dot * ksc[s] * SCALE_ - BASE_);
        ls += wgt;
        const float wv = wgt * vsc[s];
        #pragma unroll
        for (int k = 0; k < 4; ++k) {
            acc[k].x += wv * (float)vs4[s][k].x;
            acc[k].y += wv * (float)vs4[s][k].y;
            acc[k].z += wv * (float)vs4[s][k].z;
            acc[k].w += wv * (float)vs4[s][k].w;
        }
    }
#undef LOADIT

    // reduce across the 8 token slots (lane bits 3..5); j-lanes hold disjoint d
    #pragma unroll
    for (int msk = 8; msk < 64; msk <<= 1) {
        #pragma unroll
        for (int k = 0; k < 4; ++k) {
            acc[k].x += __shfl_xor(acc[k].x, msk, 64);
            acc[k].y += __shfl_xor(acc[k].y, msk, 64);
            acc[k].z += __shfl_xor(acc[k].z, msk, 64);
            acc[k].w += __shfl_xor(acc[k].w, msk, 64);
        }
        ls += __shfl_xor(ls, msk, 64);
    }
    if (t == 0) {
        float* dst = pv_c + ((size_t)(c * HKV_ + kh) * 4 + g) * D_;
        #pragma unroll
        for (int k = 0; k < 4; ++k) *(float4*)(dst + (j + 8 * k) * 4) = acc[k];
        if (j == 0) l_c[(c * HKV_ + kh) * 4 + g] = ls;
    }
}

// ---------------- kernel 4: combine (pure sums, fixed base) ----------------
__global__ __launch_bounds__(128) void k_combine(
    const float* __restrict__ pv_c, const float* __restrict__ l_c,
    const float* __restrict__ qkv, float* __restrict__ attn)
{
    const int h = blockIdx.x;        // 32 blocks
    const int d = threadIdx.x;       // 128
    const int kh = h >> 2, g = h & 3;

    __shared__ float sred[128];
    sred[d] = qkv[h * D_ + d] * qkv[4096 + kh * D_ + d];
    __syncthreads();
    for (int s2 = 64; s2 > 0; s2 >>= 1) {
        if (d < s2) sred[d] += sred[d + s2];
        __syncthreads();
    }
    const float pc = __expf(sred[0] * SCALE_ - BASE_);  // current-token weight

    float pv = 0.f, dsum = 0.f;
    #pragma unroll 8
    for (int c = 0; c < NCHUNK; ++c) {
        pv   += pv_c[((size_t)(c * HKV_ + kh) * 4 + g) * D_ + d];
        dsum += l_c[(c * HKV_ + kh) * 4 + g];
    }
    const float vcur = qkv[5120 + kh * D_ + d];
    attn[h * D_ + d] = (pv + pc * vcur) / (dsum + pc);
}

// ---------------- kernel 5: output GEMV split-K partials ----------------
__global__ __launch_bounds__(256) void k_out_part(
    const float* __restrict__ attn, const float* __restrict__ Wo,
    float* __restrict__ opart)
{
    const int j0 = blockIdx.x * 1024 + threadIdx.x * 4;  // 4 col-blocks
    const int i0 = blockIdx.y * (HID_ / SPLIT);
    __shared__ float hs[HID_ / SPLIT];
    if (threadIdx.x < HID_ / SPLIT) hs[threadIdx.x] = attn[i0 + threadIdx.x];
    __syncthreads();
    float4 acc = {0.f, 0.f, 0.f, 0.f};
    const float* p = Wo + (size_t)i0 * HID_ + j0;
    #pragma unroll 8
    for (int i = 0; i < HID_ / SPLIT; ++i) {
        const float4 wv = *(const float4*)(p + (size_t)i * HID_);
        const float h = hs[i];
        acc.x += h * wv.x; acc.y += h * wv.y; acc.z += h * wv.z; acc.w += h * wv.w;
    }
    *(float4*)&opart[(size_t)blockIdx.y * HID_ + j0] = acc;
}

// ---------------- kernel 6: reduce output partials ----------------
__global__ __launch_bounds__(256) void k_out_reduce(
    const float* __restrict__ opart, float* __restrict__ out)
{
    const int j = blockIdx.x * 256 + threadIdx.x;  // 16 blocks
    float s = 0.f;
    #pragma unroll 8
    for (int k = 0; k < SPLIT; ++k) s += opart[(size_t)k * HID_ + j];
    out[j] = s;
}

extern "C" void kernel_launch(void* const* d_in, const int* in_sizes, int n_in,
                              void* d_out, int out_size, void* d_ws, size_t ws_size,
                              hipStream_t stream) {
    const float* hid    = (const float*)d_in[0];
    const int*   kqx    = (const int*)d_in[1];
    const float* kscale = (const float*)d_in[2];
    const int*   vqx    = (const int*)d_in[3];
    const float* vscale = (const float*)d_in[4];
    const float* cosv   = (const float*)d_in[5];
    const float* sinv   = (const float*)d_in[6];
    const float* Wq     = (const float*)d_in[7];
    const float* Wk     = (const float*)d_in[8];
    const float* Wv     = (const float*)d_in[9];
    const float* Wo     = (const float*)d_in[10];
    float* ws  = (float*)d_ws;
    float* out = (float*)d_out;

    k_sweep     <<<dim3(1024),     256, 0, stream>>>(kqx, vqx, (int*)(ws + WS_OPART));
    k_qkv_part  <<<dim3(6, SPLIT), 256, 0, stream>>>(hid, Wq, Wk, Wv, ws + WS_QKV_PART);
    k_qkv_reduce<<<dim3(24),       256, 0, stream>>>(ws + WS_QKV_PART, cosv, sinv, ws + WS_QKV);
    k_attn      <<<dim3(HKV_, NCHUNK), 256, 0, stream>>>(kqx, kscale, vqx, vscale,
                                                         ws + WS_QKV, ws + WS_PV_C,
                                                         ws + WS_L_C);
    k_combine   <<<dim3(H_),       128, 0, stream>>>(ws + WS_PV_C, ws + WS_L_C,
                                                     ws + WS_QKV, ws + WS_ATTN);
    k_out_part  <<<dim3(4, SPLIT), 256, 0, stream>>>(ws + WS_ATTN, Wo, ws + WS_OPART);
    k_out_reduce<<<dim3(16),       256, 0, stream>>>(ws + WS_OPART, out);
}

// Round 14
// 145.477 us; speedup vs baseline: 1.2594x; 1.2594x over previous
//
#include <hip/hip_runtime.h>
#include <hip/hip_bf16.h>

#define H_    32
#define HKV_  8
#define D_    128
#define HID_  4096
#define NQKV  6144            // 4096 + 1024 + 1024
#define SPLIT 128             // split-K for the GEMVs (rows per chunk = 32)
#define CHUNK 256             // tokens per attention block
#define NIT   (CHUNK / 8)     // 32 iterations, 8 tokens each per wave
#define S_    32768
#define NCHUNK (S_ / CHUNK)   // 128
#define SCALE_ 0.08838834764831843f  // 1/sqrt(128)
#define BASE_  8.0f           // fixed softmax base: wgt = exp(s - 8), exact (cancels)

// workspace layout (float offsets)
#define WS_QKV_PART 0                       // [SPLIT][NQKV]          786432
#define WS_QKV      786432                  // [NQKV]                 6144
#define WS_PV_C     792576                  // [NCHUNK][HKV][4][D]    524288
#define WS_L_C      1316864                 // [NCHUNK][HKV][4]       4096
#define WS_ATTN     1320960                 // [H*D]                  4096
#define WS_OPART    1325056                 // [SPLIT][HID]           524288

// ---------------- kernel 1: QKV GEMV split-K partials ----------------
__global__ __launch_bounds__(256) void k_qkv_part(
    const float* __restrict__ hid, const float* __restrict__ Wq,
    const float* __restrict__ Wk, const float* __restrict__ Wv,
    float* __restrict__ part)
{
    const int j0 = blockIdx.x * 1024 + threadIdx.x * 4;   // 6 col-blocks of 1024
    const int i0 = blockIdx.y * (HID_ / SPLIT);           // 32-row chunk
    __shared__ float hs[HID_ / SPLIT];
    if (threadIdx.x < HID_ / SPLIT) hs[threadIdx.x] = hid[i0 + threadIdx.x];
    __syncthreads();

    const float* W; int ldw; int col;
    if (j0 < 4096)       { W = Wq; ldw = 4096; col = j0; }
    else if (j0 < 5120)  { W = Wk; ldw = 1024; col = j0 - 4096; }
    else                 { W = Wv; ldw = 1024; col = j0 - 5120; }

    float4 acc = {0.f, 0.f, 0.f, 0.f};
    const float* p = W + (size_t)i0 * ldw + col;
    #pragma unroll 8
    for (int i = 0; i < HID_ / SPLIT; ++i) {
        const float4 wv = *(const float4*)(p + (size_t)i * ldw);
        const float h = hs[i];
        acc.x += h * wv.x; acc.y += h * wv.y; acc.z += h * wv.z; acc.w += h * wv.w;
    }
    *(float4*)&part[(size_t)blockIdx.y * NQKV + j0] = acc;
}

// ---------------- kernel 2: reduce partials + RoPE ----------------
__global__ __launch_bounds__(256) void k_qkv_reduce(
    const float* __restrict__ part, const float* __restrict__ cosv,
    const float* __restrict__ sinv, float* __restrict__ qkv)
{
    const int j = blockIdx.x * 256 + threadIdx.x;  // 24 blocks
    float s = 0.f;
    #pragma unroll 8
    for (int k = 0; k < SPLIT; ++k) s += part[(size_t)k * NQKV + j];
    __shared__ float buf[256];
    buf[threadIdx.x] = s;
    __syncthreads();
    float out = s;
    if (j < 5120) {  // q and k get RoPE; v passes through
        const int d = j & 127;
        const float rot = (d < 64) ? -buf[threadIdx.x + 64] : buf[threadIdx.x - 64];
        out = s * cosv[d] + rot * sinv[d];
    }
    qkv[j] = out;
}

// ---------------- kernel 3: fused attention, depth-4 register pipeline ----------------
// block = 256 thr = 4 waves; wave g = head (kh*4+g); lane = t*8+j.
// 4 static staging slots (slot = it&3, compile-time under unroll 4) hold
// K/V/scales for iterations it..it+3 -> 16-24 KB per wave in flight through
// the dot/shfl/exp tail (Little's law: the in-flight bytes ARE the lever; the
// R13 A/B put this structure at ~47-50 us vs 82 for the 1-deep LDS version).
// __launch_bounds__(256,2) lets the allocator keep ~185 VGPRs instead of
// sinking the loads (R7's failure mode).
// Fixed-base softmax: wgt = exp(s - 8), exact (base cancels in final ratio).
__global__ __launch_bounds__(256, 2) void k_attn(
    const int* __restrict__ kqx, const float* __restrict__ kscale,
    const int* __restrict__ vqx, const float* __restrict__ vscale,
    const float* __restrict__ qkv, float* __restrict__ pv_c,
    float* __restrict__ l_c)
{
    const int kh = blockIdx.x;
    const int c  = blockIdx.y;
    const int c0 = c * CHUNK;
    const int tid = threadIdx.x;
    const int g = tid >> 6;          // wave = head-in-group
    const int l = tid & 63;
    const int t = l >> 3, j = l & 7;

    float4 qf[4];
    #pragma unroll
    for (int k = 0; k < 4; ++k)
        qf[k] = *(const float4*)&qkv[(kh * 4 + g) * D_ + (j + 8 * k) * 4];

    float ls = 0.f;
    float4 acc[4];
    #pragma unroll
    for (int k = 0; k < 4; ++k) acc[k] = make_float4(0.f, 0.f, 0.f, 0.f);

    int4 ks[4][4], vs4[4][4];
    float ksc[4], vsc[4];

#define LOADIT(slot, it_) do {                                               \
        const int tok_ = c0 + (it_) * 8 + t;                                 \
        const size_t row_ = ((size_t)tok_ * HKV_ + kh) * D_;                 \
        _Pragma("unroll")                                                    \
        for (int k2 = 0; k2 < 4; ++k2) {                                     \
            ks[slot][k2]  = *(const int4*)(kqx + row_ + (j + 8 * k2) * 4);   \
            vs4[slot][k2] = *(const int4*)(vqx + row_ + (j + 8 * k2) * 4);   \
        }                                                                    \
        ksc[slot] = kscale[(size_t)tok_ * HKV_ + kh];                        \
        vsc[slot] = vscale[(size_t)tok_ * HKV_ + kh];                        \
    } while (0)

    LOADIT(0, 0); LOADIT(1, 1); LOADIT(2, 2);

    #pragma unroll 4
    for (int it = 0; it < NIT; ++it) {
        const int s = it & 3;            // static per unrolled copy
        if (it + 3 < NIT) LOADIT((it + 3) & 3, it + 3);

        float d0 = (float)ks[s][0].x * qf[0].x + (float)ks[s][0].y * qf[0].y +
                   (float)ks[s][0].z * qf[0].z + (float)ks[s][0].w * qf[0].w;
        float d1 = (float)ks[s][1].x * qf[1].x + (float)ks[s][1].y * qf[1].y +
                   (float)ks[s][1].z * qf[1].z + (float)ks[s][1].w * qf[1].w;
        float d2 = (float)ks[s][2].x * qf[2].x + (float)ks[s][2].y * qf[2].y +
                   (float)ks[s][2].z * qf[2].z + (float)ks[s][2].w * qf[2].w;
        float d3 = (float)ks[s][3].x * qf[3].x + (float)ks[s][3].y * qf[3].y +
                   (float)ks[s][3].z * qf[3].z + (float)ks[s][3].w * qf[3].w;
        float dot = (d0 + d1) + (d2 + d3);
        dot += __shfl_xor(dot, 1, 64);
        dot += __shfl_xor(dot, 2, 64);
        dot += __shfl_xor(dot, 4, 64);

        const float wgt = __expf(dot * ksc[s] * SCALE_ - BASE_);
        ls += wgt;
        const float wv = wgt * vsc[s];
        #pragma unroll
        for (int k = 0; k < 4; ++k) {
            acc[k].x += wv * (float)vs4[s][k].x;
            acc[k].y += wv * (float)vs4[s][k].y;
            acc[k].z += wv * (float)vs4[s][k].z;
            acc[k].w += wv * (float)vs4[s][k].w;
        }
    }
#undef LOADIT

    // reduce across the 8 token slots (lane bits 3..5); j-lanes hold disjoint d
    #pragma unroll
    for (int msk = 8; msk < 64; msk <<= 1) {
        #pragma unroll
        for (int k = 0; k < 4; ++k) {
            acc[k].x += __shfl_xor(acc[k].x, msk, 64);
            acc[k].y += __shfl_xor(acc[k].y, msk, 64);
            acc[k].z += __shfl_xor(acc[k].z, msk, 64);
            acc[k].w += __shfl_xor(acc[k].w, msk, 64);
        }
        ls += __shfl_xor(ls, msk, 64);
    }
    if (t == 0) {
        float* dst = pv_c + ((size_t)(c * HKV_ + kh) * 4 + g) * D_;
        #pragma unroll
        for (int k = 0; k < 4; ++k) *(float4*)(dst + (j + 8 * k) * 4) = acc[k];
        if (j == 0) l_c[(c * HKV_ + kh) * 4 + g] = ls;
    }
}

// ---------------- kernel 4: combine (pure sums, fixed base) ----------------
__global__ __launch_bounds__(128) void k_combine(
    const float* __restrict__ pv_c, const float* __restrict__ l_c,
    const float* __restrict__ qkv, float* __restrict__ attn)
{
    const int h = blockIdx.x;        // 32 blocks
    const int d = threadIdx.x;       // 128
    const int kh = h >> 2, g = h & 3;

    __shared__ float sred[128];
    sred[d] = qkv[h * D_ + d] * qkv[4096 + kh * D_ + d];
    __syncthreads();
    for (int s2 = 64; s2 > 0; s2 >>= 1) {
        if (d < s2) sred[d] += sred[d + s2];
        __syncthreads();
    }
    const float pc = __expf(sred[0] * SCALE_ - BASE_);  // current-token weight

    float pv = 0.f, dsum = 0.f;
    #pragma unroll 8
    for (int c = 0; c < NCHUNK; ++c) {
        pv   += pv_c[((size_t)(c * HKV_ + kh) * 4 + g) * D_ + d];
        dsum += l_c[(c * HKV_ + kh) * 4 + g];
    }
    const float vcur = qkv[5120 + kh * D_ + d];
    attn[h * D_ + d] = (pv + pc * vcur) / (dsum + pc);
}

// ---------------- kernel 5: output GEMV split-K partials ----------------
__global__ __launch_bounds__(256) void k_out_part(
    const float* __restrict__ attn, const float* __restrict__ Wo,
    float* __restrict__ opart)
{
    const int j0 = blockIdx.x * 1024 + threadIdx.x * 4;  // 4 col-blocks
    const int i0 = blockIdx.y * (HID_ / SPLIT);
    __shared__ float hs[HID_ / SPLIT];
    if (threadIdx.x < HID_ / SPLIT) hs[threadIdx.x] = attn[i0 + threadIdx.x];
    __syncthreads();
    float4 acc = {0.f, 0.f, 0.f, 0.f};
    const float* p = Wo + (size_t)i0 * HID_ + j0;
    #pragma unroll 8
    for (int i = 0; i < HID_ / SPLIT; ++i) {
        const float4 wv = *(const float4*)(p + (size_t)i * HID_);
        const float h = hs[i];
        acc.x += h * wv.x; acc.y += h * wv.y; acc.z += h * wv.z; acc.w += h * wv.w;
    }
    *(float4*)&opart[(size_t)blockIdx.y * HID_ + j0] = acc;
}

// ---------------- kernel 6: reduce output partials ----------------
__global__ __launch_bounds__(256) void k_out_reduce(
    const float* __restrict__ opart, float* __restrict__ out)
{
    const int j = blockIdx.x * 256 + threadIdx.x;  // 16 blocks
    float s = 0.f;
    #pragma unroll 8
    for (int k = 0; k < SPLIT; ++k) s += opart[(size_t)k * HID_ + j];
    out[j] = s;
}

extern "C" void kernel_launch(void* const* d_in, const int* in_sizes, int n_in,
                              void* d_out, int out_size, void* d_ws, size_t ws_size,
                              hipStream_t stream) {
    const float* hid    = (const float*)d_in[0];
    const int*   kqx    = (const int*)d_in[1];
    const float* kscale = (const float*)d_in[2];
    const int*   vqx    = (const int*)d_in[3];
    const float* vscale = (const float*)d_in[4];
    const float* cosv   = (const float*)d_in[5];
    const float* sinv   = (const float*)d_in[6];
    const float* Wq     = (const float*)d_in[7];
    const float* Wk     = (const float*)d_in[8];
    const float* Wv     = (const float*)d_in[9];
    const float* Wo     = (const float*)d_in[10];
    float* ws  = (float*)d_ws;
    float* out = (float*)d_out;

    k_qkv_part  <<<dim3(6, SPLIT), 256, 0, stream>>>(hid, Wq, Wk, Wv, ws + WS_QKV_PART);
    k_qkv_reduce<<<dim3(24),       256, 0, stream>>>(ws + WS_QKV_PART, cosv, sinv, ws + WS_QKV);
    k_attn      <<<dim3(HKV_, NCHUNK), 256, 0, stream>>>(kqx, kscale, vqx, vscale,
                                                         ws + WS_QKV, ws + WS_PV_C,
                                                         ws + WS_L_C);
    k_combine   <<<dim3(H_),       128, 0, stream>>>(ws + WS_PV_C, ws + WS_L_C,
                                                     ws + WS_QKV, ws + WS_ATTN);
    k_out_part  <<<dim3(4, SPLIT), 256, 0, stream>>>(ws + WS_ATTN, Wo, ws + WS_OPART);
    k_out_reduce<<<dim3(16),       256, 0, stream>>>(ws + WS_OPART, out);
}